// Round 6
// baseline (757.393 us; speedup 1.0000x reference)
//
#include <hip/hip_runtime.h>

#define NN 100000
#define NE 3200000
#define NB 1021        // buckets
#define BNODES 98      // nodes per bucket (98*1021 >= NN)
#define NBLK 256       // partition blocks
#define CH 12500       // edges per partition block (NBLK*CH == NE, CH%4==0)
#define BCAP2 3712     // per-bucket LDS staging cap (mean 3136, sigma 56 -> +10 sigma)

typedef unsigned int uint;

// ---- bf16 helpers (RTNE) ----
__device__ inline uint bfr(float f) {
  uint u = __float_as_uint(f);
  return (u + 0x7fffu + ((u >> 16) & 1u)) >> 16;
}
__device__ inline uint packbf(float a, float b) { return bfr(a) | (bfr(b) << 16); }
__device__ inline void addq(uint4 q, float* a) {
  uint u[4] = {q.x, q.y, q.z, q.w};
#pragma unroll
  for (int j = 0; j < 4; ++j) {
    a[2 * j]     += __uint_as_float(u[j] << 16);
    a[2 * j + 1] += __uint_as_float(u[j] & 0xffff0000u);
  }
}

// ---------------- P1: per-block bucket histogram (LDS), no global atomics ----------------
__global__ __launch_bounds__(256) void pcount_kernel(const int* __restrict__ dst,
                                                     int* __restrict__ cntmat) {
  __shared__ int cnt[NB];
  int bk = blockIdx.x, tid = threadIdx.x;
  for (int j = tid; j < NB; j += 256) cnt[j] = 0;
  __syncthreads();
  int base = bk * CH;
  for (int i = base + tid * 4; i < base + CH; i += 1024) {
    int4 d4 = *(const int4*)&dst[i];
    atomicAdd(&cnt[(uint)d4.x / (uint)BNODES], 1);
    atomicAdd(&cnt[(uint)d4.y / (uint)BNODES], 1);
    atomicAdd(&cnt[(uint)d4.z / (uint)BNODES], 1);
    atomicAdd(&cnt[(uint)d4.w / (uint)BNODES], 1);
  }
  __syncthreads();
  for (int j = tid; j < NB; j += 256) cntmat[(size_t)j * NBLK + bk] = cnt[j];
}

// ---------------- P2a: bucket totals ----------------
__global__ __launch_bounds__(256) void rowsum_kernel(const int* __restrict__ cntmat,
                                                     int* __restrict__ btotal) {
  int b = blockIdx.x, t = threadIdx.x;
  int v = cntmat[(size_t)b * NBLK + t];
#pragma unroll
  for (int off = 32; off >= 1; off >>= 1) v += __shfl_xor(v, off, 64);
  __shared__ int ws[4];
  if ((t & 63) == 0) ws[t >> 6] = v;
  __syncthreads();
  if (t == 0) btotal[b] = ws[0] + ws[1] + ws[2] + ws[3];
}

// ---------------- P2b: scan bucket totals -> bucket bases ----------------
__global__ __launch_bounds__(1024) void bucket_scan_kernel(const int* __restrict__ btotal,
                                                           int* __restrict__ bbase,
                                                           int* __restrict__ row_ptr) {
  __shared__ int sh[1024];
  int i = threadIdx.x;
  int v = (i < NB) ? btotal[i] : 0;
  sh[i] = v;
  __syncthreads();
  for (int off = 1; off < 1024; off <<= 1) {
    int t = (i >= off) ? sh[i - off] : 0;
    __syncthreads();
    sh[i] += t;
    __syncthreads();
  }
  if (i < NB) bbase[i] = sh[i] - v;
  if (i == 0) row_ptr[NN] = NE;
}

// ---------------- P2c: per-(bucket,block) offsets ----------------
__global__ __launch_bounds__(256) void offsets_kernel(const int* __restrict__ cntmat,
                                                      const int* __restrict__ bbase,
                                                      int* __restrict__ offmat) {
  __shared__ int sh[256];
  int b = blockIdx.x, t = threadIdx.x;
  int v = cntmat[(size_t)b * NBLK + t];
  sh[t] = v;
  __syncthreads();
  for (int off = 1; off < 256; off <<= 1) {
    int u = (t >= off) ? sh[t - off] : 0;
    __syncthreads();
    sh[t] += u;
    __syncthreads();
  }
  offmat[(size_t)b * NBLK + t] = bbase[b] + sh[t] - v;  // exclusive prefix
}

// ---------------- P3: scatter edges into bucket-contiguous store (packed 4B) ----------------
__global__ __launch_bounds__(256) void pscatter_kernel(const int* __restrict__ src,
                                                       const int* __restrict__ dst,
                                                       const int* __restrict__ offmat,
                                                       int* __restrict__ store) {
  __shared__ int lcur[NB];
  int bk = blockIdx.x, tid = threadIdx.x;
  for (int j = tid; j < NB; j += 256) lcur[j] = offmat[(size_t)j * NBLK + bk];
  __syncthreads();
  int base = bk * CH;
  for (int i = base + tid * 4; i < base + CH; i += 1024) {
    int4 d4 = *(const int4*)&dst[i];
    int4 s4 = *(const int4*)&src[i];
    int dd[4] = {d4.x, d4.y, d4.z, d4.w};
    int ss[4] = {s4.x, s4.y, s4.z, s4.w};
#pragma unroll
    for (int j = 0; j < 4; ++j) {
      uint b = (uint)dd[j] / (uint)BNODES;
      int dl = dd[j] - (int)(b * BNODES);
      int pos = atomicAdd(&lcur[b], 1);
      store[pos] = ss[j] | (dl << 17);  // src in [0,2^17), dl in [0,98)
    }
  }
}

// ---------------- P4: per-bucket CSR build + per-row src sort + row_ptr + dinv ----------------
__global__ __launch_bounds__(256) void build_kernel(const int* __restrict__ btotal,
                                                    const int* __restrict__ bbase,
                                                    const int* __restrict__ store,
                                                    int* __restrict__ row_ptr,
                                                    float* __restrict__ dinv,
                                                    int* __restrict__ csr_src) {
  __shared__ int cnt[BNODES];
  __shared__ int excl[BNODES];
  __shared__ int s_in[BCAP2];
  __shared__ int s_out[BCAP2];
  int b = blockIdx.x, tid = threadIdx.x;
  int nb0 = b * BNODES;
  int nn = min(BNODES, NN - nb0);
  for (int j = tid; j < nn; j += 256) cnt[j] = 0;
  __syncthreads();
  int sz = btotal[b], bb = bbase[b];
  const int* bs = store + bb;
  // stage packed edges into LDS + per-node count
  for (int e = tid; e < sz; e += 256) {
    int p = bs[e];
    s_in[e] = p;
    atomicAdd(&cnt[(uint)p >> 17], 1);
  }
  __syncthreads();
  if (tid == 0) {
    int run = 0;
    for (int j = 0; j < nn; ++j) { excl[j] = run; run += cnt[j]; }
  }
  __syncthreads();
  for (int j = tid; j < nn; j += 256) {
    row_ptr[nb0 + j] = bb + excl[j];
    dinv[nb0 + j] = rsqrtf((float)(cnt[j] + 1));
  }
  __syncthreads();
  for (int j = tid; j < nn; j += 256) cnt[j] = 0;  // reuse as cursor
  __syncthreads();
  // scatter into per-row segments (LDS)
  for (int e = tid; e < sz; e += 256) {
    int p = s_in[e];
    int dl = (int)((uint)p >> 17);
    int pos = atomicAdd(&cnt[dl], 1);
    s_out[excl[dl] + pos] = p & 0x1FFFF;
  }
  __syncthreads();
  // sort each row ascending (one thread per row, insertion sort in LDS)
  for (int j = tid; j < nn; j += 256) {
    int lo = excl[j], len = cnt[j];
    for (int i = 1; i < len; ++i) {
      int key = s_out[lo + i];
      int k = i - 1;
      while (k >= 0 && s_out[lo + k] > key) {
        s_out[lo + k + 1] = s_out[lo + k];
        --k;
      }
      s_out[lo + k + 1] = key;
    }
  }
  __syncthreads();
  // coalesced write-out
  for (int e = tid; e < sz; e += 256) csr_src[bb + e] = s_out[e];
}

// ---------------- fp32 GEMM: C[M][N] = (X[M][128] @ W[128][N]) * dinv[row], opt bf16 out ----
template <int N, bool OUTBF>
__global__ __launch_bounds__(512) void gemm_kernel(const float* __restrict__ X,
                                                   const float* __restrict__ W,
                                                   const float* __restrict__ dinv,
                                                   void* __restrict__ Cv, int M) {
  constexpr int BM = 128, BN = 64, BK = 32, K = 128;
  __shared__ float XsT[BK][BM + 4];
  __shared__ float Ws[BK][BN];
  int tid = threadIdx.x;
  int row0 = blockIdx.x * BM;
  int col0 = blockIdx.y * BN;
  int tx = tid & 15;
  int ty = tid >> 4;

  float acc[4][4];
#pragma unroll
  for (int i = 0; i < 4; ++i)
#pragma unroll
    for (int j = 0; j < 4; ++j) acc[i][j] = 0.f;

  for (int k0 = 0; k0 < K; k0 += BK) {
    {
      int r = tid >> 4;
      int c4 = (tid & 15) * 4;
      *(float4*)&Ws[r][c4] = *(const float4*)&W[(size_t)(k0 + r) * N + col0 + c4];
    }
#pragma unroll
    for (int i = 0; i < 2; ++i) {
      int idx = tid + i * 512;
      int r = idx >> 3;
      int c = (idx & 7) * 4;
      float4 v = make_float4(0.f, 0.f, 0.f, 0.f);
      if (row0 + r < M) v = *(const float4*)&X[(size_t)(row0 + r) * K + k0 + c];
      XsT[c + 0][r] = v.x;
      XsT[c + 1][r] = v.y;
      XsT[c + 2][r] = v.z;
      XsT[c + 3][r] = v.w;
    }
    __syncthreads();

#pragma unroll
    for (int kk = 0; kk < BK; ++kk) {
      float4 a = *(float4*)&XsT[kk][ty * 4];
      float4 b = *(float4*)&Ws[kk][tx * 4];
      float av[4] = {a.x, a.y, a.z, a.w};
      float bv[4] = {b.x, b.y, b.z, b.w};
#pragma unroll
      for (int i = 0; i < 4; ++i)
#pragma unroll
        for (int j = 0; j < 4; ++j) acc[i][j] = fmaf(av[i], bv[j], acc[i][j]);
    }
    __syncthreads();
  }

#pragma unroll
  for (int i = 0; i < 4; ++i) {
    int row = row0 + ty * 4 + i;
    if (row < M) {
      float s = dinv[row];
      if (OUTBF) {
        ushort* Cb = (ushort*)Cv;
        uint2 st;
        st.x = packbf(acc[i][0] * s, acc[i][1] * s);
        st.y = packbf(acc[i][2] * s, acc[i][3] * s);
        *(uint2*)&Cb[(size_t)row * N + col0 + tx * 4] = st;
      } else {
        float4 st = make_float4(acc[i][0] * s, acc[i][1] * s, acc[i][2] * s, acc[i][3] * s);
        *(float4*)&((float*)Cv)[(size_t)row * N + col0 + tx * 4] = st;
      }
    }
  }
}

// ---------------- bf16-gather aggregation (C=128): H fp32 = dn*(sum bf16 Tp) + b, relu ----
__global__ __launch_bounds__(256) void agg_bf16_kernel(const uint4* __restrict__ Tq,
                                                       const int* __restrict__ row_ptr,
                                                       const int* __restrict__ csr_src,
                                                       const float* __restrict__ dinv,
                                                       const float* __restrict__ bias,
                                                       float* __restrict__ H, int n) {
  int t = blockIdx.x * 256 + threadIdx.x;
  int node = t >> 4;
  int lane = t & 15;   // 16 lanes/node, 8 channels/lane
  if (node >= n) return;

  float dn = dinv[node];
  float a0[8], a1[8], a2[8], a3[8];
#pragma unroll
  for (int c = 0; c < 8; ++c) { a0[c] = 0.f; a1[c] = 0.f; a2[c] = 0.f; a3[c] = 0.f; }
  addq(Tq[(size_t)node * 16 + lane], a0);  // self term (prescaled)

  int beg = row_ptr[node], end = row_ptr[node + 1];
  int e = beg;
  int ae = min(end, (beg + 3) & ~3);
  for (; e < ae; ++e) addq(Tq[(size_t)csr_src[e] * 16 + lane], a0);
  for (; e + 4 <= end; e += 4) {
    int4 s4 = *(const int4*)&csr_src[e];
    uint4 q0 = Tq[(size_t)s4.x * 16 + lane];
    uint4 q1 = Tq[(size_t)s4.y * 16 + lane];
    uint4 q2 = Tq[(size_t)s4.z * 16 + lane];
    uint4 q3 = Tq[(size_t)s4.w * 16 + lane];
    addq(q0, a0); addq(q1, a1); addq(q2, a2); addq(q3, a3);
  }
  for (; e < end; ++e) addq(Tq[(size_t)csr_src[e] * 16 + lane], a0);

  float4 bv0 = *(const float4*)&bias[lane * 8];
  float4 bv1 = *(const float4*)&bias[lane * 8 + 4];
  float bb[8] = {bv0.x, bv0.y, bv0.z, bv0.w, bv1.x, bv1.y, bv1.z, bv1.w};
  float h[8];
#pragma unroll
  for (int c = 0; c < 8; ++c) {
    h[c] = fmaf(dn, (a0[c] + a1[c]) + (a2[c] + a3[c]), bb[c]);
    h[c] = fmaxf(h[c], 0.f);
  }
  float* Hrow = &H[(size_t)node * 128 + lane * 8];
  *(float4*)&Hrow[0] = make_float4(h[0], h[1], h[2], h[3]);
  *(float4*)&Hrow[4] = make_float4(h[4], h[5], h[6], h[7]);
}

// ---------------- fp32 aggregation (C=64) + fused final linear ----------------
__global__ __launch_bounds__(256) void agg_f32_kernel(const float* __restrict__ Tp,
                                                      const int* __restrict__ row_ptr,
                                                      const int* __restrict__ csr_src,
                                                      const float* __restrict__ dinv,
                                                      const float* __restrict__ bias,
                                                      float* __restrict__ H,
                                                      const float* __restrict__ Wout,
                                                      const float* __restrict__ bout,
                                                      float* __restrict__ Out, int n) {
  constexpr int LPN = 16;
  int t = blockIdx.x * 256 + threadIdx.x;
  int node = t / LPN;
  int lane = t % LPN;
  if (node >= n) return;

  const float4* Trow = (const float4*)Tp;
  float dn = dinv[node];

  float4 acc[4];
  acc[0] = Trow[(size_t)node * LPN + lane];
#pragma unroll
  for (int i = 1; i < 4; ++i) acc[i] = make_float4(0.f, 0.f, 0.f, 0.f);

  int beg = row_ptr[node], end = row_ptr[node + 1];
  int e = beg;
  int ae = min(end, (beg + 3) & ~3);
  for (; e < ae; ++e) {
    float4 v = Trow[(size_t)csr_src[e] * LPN + lane];
    acc[0].x += v.x; acc[0].y += v.y; acc[0].z += v.z; acc[0].w += v.w;
  }
  for (; e + 4 <= end; e += 4) {
    int4 ia = *(const int4*)&csr_src[e];
    float4 v0 = Trow[(size_t)ia.x * LPN + lane];
    float4 v1 = Trow[(size_t)ia.y * LPN + lane];
    float4 v2 = Trow[(size_t)ia.z * LPN + lane];
    float4 v3 = Trow[(size_t)ia.w * LPN + lane];
    acc[0].x += v0.x; acc[0].y += v0.y; acc[0].z += v0.z; acc[0].w += v0.w;
    acc[1].x += v1.x; acc[1].y += v1.y; acc[1].z += v1.z; acc[1].w += v1.w;
    acc[2].x += v2.x; acc[2].y += v2.y; acc[2].z += v2.z; acc[2].w += v2.w;
    acc[3].x += v3.x; acc[3].y += v3.y; acc[3].z += v3.z; acc[3].w += v3.w;
  }
  for (; e < end; ++e) {
    float4 v = Trow[(size_t)csr_src[e] * LPN + lane];
    acc[0].x += v.x; acc[0].y += v.y; acc[0].z += v.z; acc[0].w += v.w;
  }
  float4 s;
  s.x = (acc[0].x + acc[1].x) + (acc[2].x + acc[3].x);
  s.y = (acc[0].y + acc[1].y) + (acc[2].y + acc[3].y);
  s.z = (acc[0].z + acc[1].z) + (acc[2].z + acc[3].z);
  s.w = (acc[0].w + acc[1].w) + (acc[2].w + acc[3].w);

  float4 bv = *(const float4*)&bias[4 * lane];
  float4 h;
  h.x = fmaf(dn, s.x, bv.x);
  h.y = fmaf(dn, s.y, bv.y);
  h.z = fmaf(dn, s.z, bv.z);
  h.w = fmaf(dn, s.w, bv.w);
  ((float4*)H)[(size_t)node * LPN + lane] = h;

  int k0 = 4 * lane;
  float p0 = h.x * Wout[(k0 + 0) * 2 + 0] + h.y * Wout[(k0 + 1) * 2 + 0] +
             h.z * Wout[(k0 + 2) * 2 + 0] + h.w * Wout[(k0 + 3) * 2 + 0];
  float p1 = h.x * Wout[(k0 + 0) * 2 + 1] + h.y * Wout[(k0 + 1) * 2 + 1] +
             h.z * Wout[(k0 + 2) * 2 + 1] + h.w * Wout[(k0 + 3) * 2 + 1];
#pragma unroll
  for (int off = 8; off >= 1; off >>= 1) {
    p0 += __shfl_xor(p0, off, 16);
    p1 += __shfl_xor(p1, off, 16);
  }
  if (lane == 0) {
    Out[(size_t)node * 2 + 0] = p0 + bout[0];
    Out[(size_t)node * 2 + 1] = p1 + bout[1];
  }
}

extern "C" void kernel_launch(void* const* d_in, const int* in_sizes, int n_in,
                              void* d_out, int out_size, void* d_ws, size_t ws_size,
                              hipStream_t stream) {
  const float* x    = (const float*)d_in[0];
  const int*   ei   = (const int*)d_in[1];
  const float* W1   = (const float*)d_in[2];
  const float* b1   = (const float*)d_in[3];
  const float* W2   = (const float*)d_in[4];
  const float* b2   = (const float*)d_in[5];
  const float* W3   = (const float*)d_in[6];
  const float* b3   = (const float*)d_in[7];
  const float* Wout = (const float*)d_in[8];
  const float* bout = (const float*)d_in[9];

  const int n = NN, E = NE;
  const int* srcp = ei;
  const int* dstp = ei + E;

  char* ws = (char*)d_ws;
  int*   cntmat  = (int*)(ws + 0);            // 1,045,504 B
  int*   btotal  = (int*)(ws + 1045504);      // pad to 4096
  int*   bbase   = (int*)(ws + 1049600);      // pad to 4096
  int*   offmat  = (int*)(ws + 1053696);      // 1,045,504 B
  int*   row_ptr = (int*)(ws + 2099200);      // 400,016 B
  float* dinv    = (float*)(ws + 2499216);    // 400,000 B
  int*   csr_src = (int*)(ws + 2899216);      // 12.8 MB (16B aligned)
  char*  bufA    = ws + 15699216;             // 25.6 MB (bf16 128ch / fp32 64ch)
  char*  bufB    = ws + 41299216;             // 51.2 MB (fp32 h, 128ch)
  int*   store   = (int*)(ws + 41299216);     // 12.8 MB, aliases bufB (dead before agg1)

  float* outp = (float*)d_out;
  float* hemb = (float*)d_out + 2 * n;

  // ---- graph build (atomic-free radix partition, per-row sorted) ----
  pcount_kernel<<<NBLK, 256, 0, stream>>>(dstp, cntmat);
  rowsum_kernel<<<NB, 256, 0, stream>>>(cntmat, btotal);
  bucket_scan_kernel<<<1, 1024, 0, stream>>>(btotal, bbase, row_ptr);
  offsets_kernel<<<NB, 256, 0, stream>>>(cntmat, bbase, offmat);
  pscatter_kernel<<<NBLK, 256, 0, stream>>>(srcp, dstp, offmat, store);
  build_kernel<<<NB, 256, 0, stream>>>(btotal, bbase, store, row_ptr, dinv, csr_src);

  // layer 1: Tp1(bf16) = (x @ W1)*dinv ; h1(fp32) = relu(dn*sum + b1)
  gemm_kernel<128, true><<<dim3((n + 127) / 128, 2), 512, 0, stream>>>(x, W1, dinv, bufA, n);
  agg_bf16_kernel<<<(n * 16 + 255) / 256, 256, 0, stream>>>(
      (const uint4*)bufA, row_ptr, csr_src, dinv, b1, (float*)bufB, n);

  // layer 2
  gemm_kernel<128, true><<<dim3((n + 127) / 128, 2), 512, 0, stream>>>(
      (const float*)bufB, W2, dinv, bufA, n);
  agg_bf16_kernel<<<(n * 16 + 255) / 256, 256, 0, stream>>>(
      (const uint4*)bufA, row_ptr, csr_src, dinv, b2, (float*)bufB, n);

  // layer 3 (fp32) + fused final linear
  gemm_kernel<64, false><<<dim3((n + 127) / 128, 1), 512, 0, stream>>>(
      (const float*)bufB, W3, dinv, bufA, n);
  agg_f32_kernel<<<(n * 16 + 255) / 256, 256, 0, stream>>>(
      (const float*)bufA, row_ptr, csr_src, dinv, b3, hemb, Wout, bout, outp, n);
}

// Round 7
// 710.673 us; speedup vs baseline: 1.0657x; 1.0657x over previous
//
#include <hip/hip_runtime.h>

#define NN 100000
#define NE 3200000
#define NB 1021        // buckets
#define BNODES 98      // nodes per bucket (98*1021 >= NN)
#define NBLK 256       // partition blocks
#define CH 12500       // edges per partition block (NBLK*CH == NE, CH%4==0)

typedef unsigned int uint;

// ---- bf16 helpers (RTNE) ----
__device__ inline uint bfr(float f) {
  uint u = __float_as_uint(f);
  return (u + 0x7fffu + ((u >> 16) & 1u)) >> 16;
}
__device__ inline uint packbf(float a, float b) { return bfr(a) | (bfr(b) << 16); }
__device__ inline void addq(uint4 q, float* a) {
  uint u[4] = {q.x, q.y, q.z, q.w};
#pragma unroll
  for (int j = 0; j < 4; ++j) {
    a[2 * j]     += __uint_as_float(u[j] << 16);
    a[2 * j + 1] += __uint_as_float(u[j] & 0xffff0000u);
  }
}

// ---------------- P1: per-block bucket histogram (LDS), no global atomics ----------------
__global__ __launch_bounds__(256) void pcount_kernel(const int* __restrict__ dst,
                                                     int* __restrict__ cntmat) {
  __shared__ int cnt[NB];
  int bk = blockIdx.x, tid = threadIdx.x;
  for (int j = tid; j < NB; j += 256) cnt[j] = 0;
  __syncthreads();
  int base = bk * CH;
  for (int i = base + tid * 4; i < base + CH; i += 1024) {
    int4 d4 = *(const int4*)&dst[i];
    atomicAdd(&cnt[(uint)d4.x / (uint)BNODES], 1);
    atomicAdd(&cnt[(uint)d4.y / (uint)BNODES], 1);
    atomicAdd(&cnt[(uint)d4.z / (uint)BNODES], 1);
    atomicAdd(&cnt[(uint)d4.w / (uint)BNODES], 1);
  }
  __syncthreads();
  for (int j = tid; j < NB; j += 256) cntmat[(size_t)j * NBLK + bk] = cnt[j];
}

// ---------------- P2a: bucket totals ----------------
__global__ __launch_bounds__(256) void rowsum_kernel(const int* __restrict__ cntmat,
                                                     int* __restrict__ btotal) {
  int b = blockIdx.x, t = threadIdx.x;
  int v = cntmat[(size_t)b * NBLK + t];
#pragma unroll
  for (int off = 32; off >= 1; off >>= 1) v += __shfl_xor(v, off, 64);
  __shared__ int ws[4];
  if ((t & 63) == 0) ws[t >> 6] = v;
  __syncthreads();
  if (t == 0) btotal[b] = ws[0] + ws[1] + ws[2] + ws[3];
}

// ---------------- P2b: scan bucket totals -> bucket bases ----------------
__global__ __launch_bounds__(1024) void bucket_scan_kernel(const int* __restrict__ btotal,
                                                           int* __restrict__ bbase,
                                                           int* __restrict__ row_ptr) {
  __shared__ int sh[1024];
  int i = threadIdx.x;
  int v = (i < NB) ? btotal[i] : 0;
  sh[i] = v;
  __syncthreads();
  for (int off = 1; off < 1024; off <<= 1) {
    int t = (i >= off) ? sh[i - off] : 0;
    __syncthreads();
    sh[i] += t;
    __syncthreads();
  }
  if (i < NB) bbase[i] = sh[i] - v;
  if (i == 0) row_ptr[NN] = NE;
}

// ---------------- P2c: per-(bucket,block) offsets ----------------
__global__ __launch_bounds__(256) void offsets_kernel(const int* __restrict__ cntmat,
                                                      const int* __restrict__ bbase,
                                                      int* __restrict__ offmat) {
  __shared__ int sh[256];
  int b = blockIdx.x, t = threadIdx.x;
  int v = cntmat[(size_t)b * NBLK + t];
  sh[t] = v;
  __syncthreads();
  for (int off = 1; off < 256; off <<= 1) {
    int u = (t >= off) ? sh[t - off] : 0;
    __syncthreads();
    sh[t] += u;
    __syncthreads();
  }
  offmat[(size_t)b * NBLK + t] = bbase[b] + sh[t] - v;  // exclusive prefix
}

// ---------------- P3: scatter edges into bucket-contiguous store (packed 4B) ----------------
__global__ __launch_bounds__(256) void pscatter_kernel(const int* __restrict__ src,
                                                       const int* __restrict__ dst,
                                                       const int* __restrict__ offmat,
                                                       int* __restrict__ store) {
  __shared__ int lcur[NB];
  int bk = blockIdx.x, tid = threadIdx.x;
  for (int j = tid; j < NB; j += 256) lcur[j] = offmat[(size_t)j * NBLK + bk];
  __syncthreads();
  int base = bk * CH;
  for (int i = base + tid * 4; i < base + CH; i += 1024) {
    int4 d4 = *(const int4*)&dst[i];
    int4 s4 = *(const int4*)&src[i];
    int dd[4] = {d4.x, d4.y, d4.z, d4.w};
    int ss[4] = {s4.x, s4.y, s4.z, s4.w};
#pragma unroll
    for (int j = 0; j < 4; ++j) {
      uint b = (uint)dd[j] / (uint)BNODES;
      int dl = dd[j] - (int)(b * BNODES);
      int pos = atomicAdd(&lcur[b], 1);
      store[pos] = ss[j] | (dl << 17);  // src in [0,2^17), dl in [0,98)
    }
  }
}

// ---------------- P4: per-bucket CSR build + row_ptr + dinv (no sort) ----------------
__global__ __launch_bounds__(256) void build_kernel(const int* __restrict__ btotal,
                                                    const int* __restrict__ bbase,
                                                    const int* __restrict__ store,
                                                    int* __restrict__ row_ptr,
                                                    float* __restrict__ dinv,
                                                    int* __restrict__ csr_src) {
  __shared__ int cnt[BNODES];
  __shared__ int excl[BNODES];
  int b = blockIdx.x, tid = threadIdx.x;
  int nb0 = b * BNODES;
  int nn = min(BNODES, NN - nb0);
  for (int j = tid; j < nn; j += 256) cnt[j] = 0;
  __syncthreads();
  int sz = btotal[b], bb = bbase[b];
  const int* bs = store + bb;
  for (int e = tid; e < sz; e += 256) atomicAdd(&cnt[(uint)bs[e] >> 17], 1);
  __syncthreads();
  if (tid == 0) {
    int run = 0;
    for (int j = 0; j < nn; ++j) { excl[j] = run; run += cnt[j]; }
  }
  __syncthreads();
  for (int j = tid; j < nn; j += 256) {
    row_ptr[nb0 + j] = bb + excl[j];
    dinv[nb0 + j] = rsqrtf((float)(cnt[j] + 1));
  }
  __syncthreads();
  for (int j = tid; j < nn; j += 256) cnt[j] = 0;  // reuse as cursor
  __syncthreads();
  for (int e = tid; e < sz; e += 256) {
    int p = bs[e];
    int dl = (int)((uint)p >> 17);
    int pos = atomicAdd(&cnt[dl], 1);
    csr_src[bb + excl[dl] + pos] = p & 0x1FFFF;
  }
}

// ---- fp32 GEMM: C_half[M][64](bf16) = (X[M][128] @ W[128][N])[:, half] * dinv[row] ----
// blockIdx.y selects the 64-col half; each half written to its own contiguous buffer.
template <int N>
__global__ __launch_bounds__(512) void gemm_kernel(const float* __restrict__ X,
                                                   const float* __restrict__ W,
                                                   const float* __restrict__ dinv,
                                                   ushort* __restrict__ C0,
                                                   ushort* __restrict__ C1, int M) {
  constexpr int BM = 128, BN = 64, BK = 32, K = 128;
  __shared__ float XsT[BK][BM + 4];
  __shared__ float Ws[BK][BN];
  int tid = threadIdx.x;
  int row0 = blockIdx.x * BM;
  int col0 = blockIdx.y * BN;
  int tx = tid & 15;
  int ty = tid >> 4;

  float acc[4][4];
#pragma unroll
  for (int i = 0; i < 4; ++i)
#pragma unroll
    for (int j = 0; j < 4; ++j) acc[i][j] = 0.f;

  for (int k0 = 0; k0 < K; k0 += BK) {
    {
      int r = tid >> 4;
      int c4 = (tid & 15) * 4;
      *(float4*)&Ws[r][c4] = *(const float4*)&W[(size_t)(k0 + r) * N + col0 + c4];
    }
#pragma unroll
    for (int i = 0; i < 2; ++i) {
      int idx = tid + i * 512;
      int r = idx >> 3;
      int c = (idx & 7) * 4;
      float4 v = make_float4(0.f, 0.f, 0.f, 0.f);
      if (row0 + r < M) v = *(const float4*)&X[(size_t)(row0 + r) * K + k0 + c];
      XsT[c + 0][r] = v.x;
      XsT[c + 1][r] = v.y;
      XsT[c + 2][r] = v.z;
      XsT[c + 3][r] = v.w;
    }
    __syncthreads();

#pragma unroll
    for (int kk = 0; kk < BK; ++kk) {
      float4 a = *(float4*)&XsT[kk][ty * 4];
      float4 b = *(float4*)&Ws[kk][tx * 4];
      float av[4] = {a.x, a.y, a.z, a.w};
      float bv[4] = {b.x, b.y, b.z, b.w};
#pragma unroll
      for (int i = 0; i < 4; ++i)
#pragma unroll
        for (int j = 0; j < 4; ++j) acc[i][j] = fmaf(av[i], bv[j], acc[i][j]);
    }
    __syncthreads();
  }

  ushort* Cb = blockIdx.y ? C1 : C0;
#pragma unroll
  for (int i = 0; i < 4; ++i) {
    int row = row0 + ty * 4 + i;
    if (row < M) {
      float s = dinv[row];
      uint2 st;
      st.x = packbf(acc[i][0] * s, acc[i][1] * s);
      st.y = packbf(acc[i][2] * s, acc[i][3] * s);
      *(uint2*)&Cb[(size_t)row * 64 + tx * 4] = st;
    }
  }
}

// ---- 64-channel bf16-gather aggregation: H[:,64 cols] fp32 = dn*(sum bf16 Tp) + b ----
// 8 lanes/node, 8 channels (uint4, 16B) per lane. Hstride in floats.
template <bool RELU, bool FUSE_OUT>
__global__ __launch_bounds__(256) void agg64_kernel(const uint4* __restrict__ Tq,
                                                    const int* __restrict__ row_ptr,
                                                    const int* __restrict__ csr_src,
                                                    const float* __restrict__ dinv,
                                                    const float* __restrict__ bias,
                                                    float* __restrict__ H, int hstride,
                                                    const float* __restrict__ Wout,
                                                    const float* __restrict__ bout,
                                                    float* __restrict__ Out, int n) {
  int t = blockIdx.x * 256 + threadIdx.x;
  int node = t >> 3;
  int lane = t & 7;   // 8 lanes/node, 8 channels/lane
  if (node >= n) return;

  float dn = dinv[node];
  float a0[8], a1[8], a2[8], a3[8];
#pragma unroll
  for (int c = 0; c < 8; ++c) { a0[c] = 0.f; a1[c] = 0.f; a2[c] = 0.f; a3[c] = 0.f; }
  addq(Tq[(size_t)node * 8 + lane], a0);  // self term (prescaled)

  int beg = row_ptr[node], end = row_ptr[node + 1];
  int e = beg;
  int ae = min(end, (beg + 3) & ~3);
  for (; e < ae; ++e) addq(Tq[(size_t)csr_src[e] * 8 + lane], a0);
  for (; e + 4 <= end; e += 4) {
    int4 s4 = *(const int4*)&csr_src[e];
    uint4 q0 = Tq[(size_t)s4.x * 8 + lane];
    uint4 q1 = Tq[(size_t)s4.y * 8 + lane];
    uint4 q2 = Tq[(size_t)s4.z * 8 + lane];
    uint4 q3 = Tq[(size_t)s4.w * 8 + lane];
    addq(q0, a0); addq(q1, a1); addq(q2, a2); addq(q3, a3);
  }
  for (; e < end; ++e) addq(Tq[(size_t)csr_src[e] * 8 + lane], a0);

  float4 bv0 = *(const float4*)&bias[lane * 8];
  float4 bv1 = *(const float4*)&bias[lane * 8 + 4];
  float bb[8] = {bv0.x, bv0.y, bv0.z, bv0.w, bv1.x, bv1.y, bv1.z, bv1.w};
  float h[8];
#pragma unroll
  for (int c = 0; c < 8; ++c) {
    h[c] = fmaf(dn, (a0[c] + a1[c]) + (a2[c] + a3[c]), bb[c]);
    if (RELU) h[c] = fmaxf(h[c], 0.f);
  }
  float* Hrow = &H[(size_t)node * hstride + lane * 8];
  *(float4*)&Hrow[0] = make_float4(h[0], h[1], h[2], h[3]);
  *(float4*)&Hrow[4] = make_float4(h[4], h[5], h[6], h[7]);

  if (FUSE_OUT) {  // 64 channels total; lane holds k = lane*8 + c
    int k0 = 8 * lane;
    float p0 = 0.f, p1 = 0.f;
#pragma unroll
    for (int c = 0; c < 8; ++c) {
      p0 = fmaf(h[c], Wout[(k0 + c) * 2 + 0], p0);
      p1 = fmaf(h[c], Wout[(k0 + c) * 2 + 1], p1);
    }
#pragma unroll
    for (int off = 4; off >= 1; off >>= 1) {
      p0 += __shfl_xor(p0, off, 8);
      p1 += __shfl_xor(p1, off, 8);
    }
    if (lane == 0) {
      Out[(size_t)node * 2 + 0] = p0 + bout[0];
      Out[(size_t)node * 2 + 1] = p1 + bout[1];
    }
  }
}

extern "C" void kernel_launch(void* const* d_in, const int* in_sizes, int n_in,
                              void* d_out, int out_size, void* d_ws, size_t ws_size,
                              hipStream_t stream) {
  const float* x    = (const float*)d_in[0];
  const int*   ei   = (const int*)d_in[1];
  const float* W1   = (const float*)d_in[2];
  const float* b1   = (const float*)d_in[3];
  const float* W2   = (const float*)d_in[4];
  const float* b2   = (const float*)d_in[5];
  const float* W3   = (const float*)d_in[6];
  const float* b3   = (const float*)d_in[7];
  const float* Wout = (const float*)d_in[8];
  const float* bout = (const float*)d_in[9];

  const int n = NN, E = NE;
  const int* srcp = ei;
  const int* dstp = ei + E;

  char* ws = (char*)d_ws;
  int*    cntmat  = (int*)(ws + 0);            // 1,045,504 B
  int*    btotal  = (int*)(ws + 1045504);      // pad to 4096
  int*    bbase   = (int*)(ws + 1049600);      // pad to 4096
  int*    offmat  = (int*)(ws + 1053696);      // 1,045,504 B
  int*    row_ptr = (int*)(ws + 2099200);      // 400,016 B
  float*  dinv    = (float*)(ws + 2499216);    // 400,000 B
  int*    csr_src = (int*)(ws + 2899216);      // 12.8 MB (16B aligned)
  ushort* bufLo   = (ushort*)(ws + 15699216);  // 12.8 MB bf16 [n,64]
  ushort* bufHi   = (ushort*)(ws + 28499216);  // 12.8 MB bf16 [n,64]
  float*  bufH    = (float*)(ws + 41299216);   // 51.2 MB fp32 [n,128]
  int*    store   = (int*)(ws + 41299216);     // 12.8 MB, aliases bufH (dead before agg1)

  float* outp = (float*)d_out;
  float* hemb = (float*)d_out + 2 * n;

  // ---- graph build (atomic-free radix partition) ----
  pcount_kernel<<<NBLK, 256, 0, stream>>>(dstp, cntmat);
  rowsum_kernel<<<NB, 256, 0, stream>>>(cntmat, btotal);
  bucket_scan_kernel<<<1, 1024, 0, stream>>>(btotal, bbase, row_ptr);
  offsets_kernel<<<NB, 256, 0, stream>>>(cntmat, bbase, offmat);
  pscatter_kernel<<<NBLK, 256, 0, stream>>>(srcp, dstp, offmat, store);
  build_kernel<<<NB, 256, 0, stream>>>(btotal, bbase, store, row_ptr, dinv, csr_src);

  int aggGrid = (n * 8 + 255) / 256;

  // layer 1: Tp1 halves (bf16) = (x @ W1)*dinv ; h1 = relu(dn*sum + b1)
  gemm_kernel<128><<<dim3((n + 127) / 128, 2), 512, 0, stream>>>(x, W1, dinv, bufLo, bufHi, n);
  agg64_kernel<true, false><<<aggGrid, 256, 0, stream>>>(
      (const uint4*)bufLo, row_ptr, csr_src, dinv, b1, bufH, 128, nullptr, nullptr, nullptr, n);
  agg64_kernel<true, false><<<aggGrid, 256, 0, stream>>>(
      (const uint4*)bufHi, row_ptr, csr_src, dinv, b1 + 64, bufH + 64, 128, nullptr, nullptr, nullptr, n);

  // layer 2
  gemm_kernel<128><<<dim3((n + 127) / 128, 2), 512, 0, stream>>>(bufH, W2, dinv, bufLo, bufHi, n);
  agg64_kernel<true, false><<<aggGrid, 256, 0, stream>>>(
      (const uint4*)bufLo, row_ptr, csr_src, dinv, b2, bufH, 128, nullptr, nullptr, nullptr, n);
  agg64_kernel<true, false><<<aggGrid, 256, 0, stream>>>(
      (const uint4*)bufHi, row_ptr, csr_src, dinv, b2 + 64, bufH + 64, 128, nullptr, nullptr, nullptr, n);

  // layer 3 (64 ch, bf16 gather) + fused final linear
  gemm_kernel<64><<<dim3((n + 127) / 128, 1), 512, 0, stream>>>(bufH, W3, dinv, bufLo, bufLo, n);
  agg64_kernel<false, true><<<aggGrid, 256, 0, stream>>>(
      (const uint4*)bufLo, row_ptr, csr_src, dinv, b3, hemb, 64, Wout, bout, outp, n);
}

// Round 8
// 631.413 us; speedup vs baseline: 1.1995x; 1.1255x over previous
//
#include <hip/hip_runtime.h>

#define NN 100000
#define NE 3200000
#define NB 1021        // buckets
#define BNODES 98      // nodes per bucket (98*1021 >= NN)
#define NBLK 256       // partition blocks
#define CH 12500       // edges per partition block (NBLK*CH == NE, CH%4==0)

typedef unsigned int uint;

// ---- bf16 helpers (RTNE) ----
__device__ inline uint bfr(float f) {
  uint u = __float_as_uint(f);
  return (u + 0x7fffu + ((u >> 16) & 1u)) >> 16;
}
__device__ inline uint packbf(float a, float b) { return bfr(a) | (bfr(b) << 16); }
__device__ inline void addq(uint4 q, float* a) {
  uint u[4] = {q.x, q.y, q.z, q.w};
#pragma unroll
  for (int j = 0; j < 4; ++j) {
    a[2 * j]     += __uint_as_float(u[j] << 16);
    a[2 * j + 1] += __uint_as_float(u[j] & 0xffff0000u);
  }
}

// ---------------- P1: per-block bucket histogram (LDS), no global atomics ----------------
__global__ __launch_bounds__(256) void pcount_kernel(const int* __restrict__ dst,
                                                     int* __restrict__ cntmat) {
  __shared__ int cnt[NB];
  int bk = blockIdx.x, tid = threadIdx.x;
  for (int j = tid; j < NB; j += 256) cnt[j] = 0;
  __syncthreads();
  int base = bk * CH;
  for (int i = base + tid * 4; i < base + CH; i += 1024) {
    int4 d4 = *(const int4*)&dst[i];
    atomicAdd(&cnt[(uint)d4.x / (uint)BNODES], 1);
    atomicAdd(&cnt[(uint)d4.y / (uint)BNODES], 1);
    atomicAdd(&cnt[(uint)d4.z / (uint)BNODES], 1);
    atomicAdd(&cnt[(uint)d4.w / (uint)BNODES], 1);
  }
  __syncthreads();
  for (int j = tid; j < NB; j += 256) cntmat[(size_t)j * NBLK + bk] = cnt[j];
}

// ---------------- P2a: bucket totals ----------------
__global__ __launch_bounds__(256) void rowsum_kernel(const int* __restrict__ cntmat,
                                                     int* __restrict__ btotal) {
  int b = blockIdx.x, t = threadIdx.x;
  int v = cntmat[(size_t)b * NBLK + t];
#pragma unroll
  for (int off = 32; off >= 1; off >>= 1) v += __shfl_xor(v, off, 64);
  __shared__ int ws[4];
  if ((t & 63) == 0) ws[t >> 6] = v;
  __syncthreads();
  if (t == 0) btotal[b] = ws[0] + ws[1] + ws[2] + ws[3];
}

// ---------------- P2b: scan bucket totals -> bucket bases ----------------
__global__ __launch_bounds__(1024) void bucket_scan_kernel(const int* __restrict__ btotal,
                                                           int* __restrict__ bbase,
                                                           int* __restrict__ row_ptr) {
  __shared__ int sh[1024];
  int i = threadIdx.x;
  int v = (i < NB) ? btotal[i] : 0;
  sh[i] = v;
  __syncthreads();
  for (int off = 1; off < 1024; off <<= 1) {
    int t = (i >= off) ? sh[i - off] : 0;
    __syncthreads();
    sh[i] += t;
    __syncthreads();
  }
  if (i < NB) bbase[i] = sh[i] - v;
  if (i == 0) row_ptr[NN] = NE;
}

// ---------------- P2c: per-(bucket,block) offsets ----------------
__global__ __launch_bounds__(256) void offsets_kernel(const int* __restrict__ cntmat,
                                                      const int* __restrict__ bbase,
                                                      int* __restrict__ offmat) {
  __shared__ int sh[256];
  int b = blockIdx.x, t = threadIdx.x;
  int v = cntmat[(size_t)b * NBLK + t];
  sh[t] = v;
  __syncthreads();
  for (int off = 1; off < 256; off <<= 1) {
    int u = (t >= off) ? sh[t - off] : 0;
    __syncthreads();
    sh[t] += u;
    __syncthreads();
  }
  offmat[(size_t)b * NBLK + t] = bbase[b] + sh[t] - v;  // exclusive prefix
}

// ---------------- P3: scatter edges into bucket-contiguous store (packed 4B) ----------------
__global__ __launch_bounds__(256) void pscatter_kernel(const int* __restrict__ src,
                                                       const int* __restrict__ dst,
                                                       const int* __restrict__ offmat,
                                                       int* __restrict__ store) {
  __shared__ int lcur[NB];
  int bk = blockIdx.x, tid = threadIdx.x;
  for (int j = tid; j < NB; j += 256) lcur[j] = offmat[(size_t)j * NBLK + bk];
  __syncthreads();
  int base = bk * CH;
  for (int i = base + tid * 4; i < base + CH; i += 1024) {
    int4 d4 = *(const int4*)&dst[i];
    int4 s4 = *(const int4*)&src[i];
    int dd[4] = {d4.x, d4.y, d4.z, d4.w};
    int ss[4] = {s4.x, s4.y, s4.z, s4.w};
#pragma unroll
    for (int j = 0; j < 4; ++j) {
      uint b = (uint)dd[j] / (uint)BNODES;
      int dl = dd[j] - (int)(b * BNODES);
      int pos = atomicAdd(&lcur[b], 1);
      store[pos] = ss[j] | (dl << 17);  // src in [0,2^17), dl in [0,98)
    }
  }
}

// ---------------- P4: per-bucket CSR build + row_ptr + dinv ----------------
__global__ __launch_bounds__(256) void build_kernel(const int* __restrict__ btotal,
                                                    const int* __restrict__ bbase,
                                                    const int* __restrict__ store,
                                                    int* __restrict__ row_ptr,
                                                    float* __restrict__ dinv,
                                                    int* __restrict__ csr_src) {
  __shared__ int cnt[BNODES];
  __shared__ int excl[BNODES];
  int b = blockIdx.x, tid = threadIdx.x;
  int nb0 = b * BNODES;
  int nn = min(BNODES, NN - nb0);
  for (int j = tid; j < nn; j += 256) cnt[j] = 0;
  __syncthreads();
  int sz = btotal[b], bb = bbase[b];
  const int* bs = store + bb;
  for (int e = tid; e < sz; e += 256) atomicAdd(&cnt[(uint)bs[e] >> 17], 1);
  __syncthreads();
  if (tid == 0) {
    int run = 0;
    for (int j = 0; j < nn; ++j) { excl[j] = run; run += cnt[j]; }
  }
  __syncthreads();
  for (int j = tid; j < nn; j += 256) {
    row_ptr[nb0 + j] = bb + excl[j];
    dinv[nb0 + j] = rsqrtf((float)(cnt[j] + 1));
  }
  __syncthreads();
  for (int j = tid; j < nn; j += 256) cnt[j] = 0;  // reuse as cursor
  __syncthreads();
  for (int e = tid; e < sz; e += 256) {
    int p = bs[e];
    int dl = (int)((uint)p >> 17);
    int pos = atomicAdd(&cnt[dl], 1);
    csr_src[bb + excl[dl] + pos] = p & 0x1FFFF;
  }
}

// ---- fp32 GEMM: C[M][N](bf16) = (X[M][128] @ W[128][N]) * dinv[row] ----
template <int N>
__global__ __launch_bounds__(512) void gemm_kernel(const float* __restrict__ X,
                                                   const float* __restrict__ W,
                                                   const float* __restrict__ dinv,
                                                   ushort* __restrict__ C, int M) {
  constexpr int BM = 128, BN = 64, BK = 32, K = 128;
  __shared__ float XsT[BK][BM + 4];
  __shared__ float Ws[BK][BN];
  int tid = threadIdx.x;
  int row0 = blockIdx.x * BM;
  int col0 = blockIdx.y * BN;
  int tx = tid & 15;
  int ty = tid >> 4;

  float acc[4][4];
#pragma unroll
  for (int i = 0; i < 4; ++i)
#pragma unroll
    for (int j = 0; j < 4; ++j) acc[i][j] = 0.f;

  for (int k0 = 0; k0 < K; k0 += BK) {
    {
      int r = tid >> 4;
      int c4 = (tid & 15) * 4;
      *(float4*)&Ws[r][c4] = *(const float4*)&W[(size_t)(k0 + r) * N + col0 + c4];
    }
#pragma unroll
    for (int i = 0; i < 2; ++i) {
      int idx = tid + i * 512;
      int r = idx >> 3;
      int c = (idx & 7) * 4;
      float4 v = make_float4(0.f, 0.f, 0.f, 0.f);
      if (row0 + r < M) v = *(const float4*)&X[(size_t)(row0 + r) * K + k0 + c];
      XsT[c + 0][r] = v.x;
      XsT[c + 1][r] = v.y;
      XsT[c + 2][r] = v.z;
      XsT[c + 3][r] = v.w;
    }
    __syncthreads();

#pragma unroll
    for (int kk = 0; kk < BK; ++kk) {
      float4 a = *(float4*)&XsT[kk][ty * 4];
      float4 b = *(float4*)&Ws[kk][tx * 4];
      float av[4] = {a.x, a.y, a.z, a.w};
      float bv[4] = {b.x, b.y, b.z, b.w};
#pragma unroll
      for (int i = 0; i < 4; ++i)
#pragma unroll
        for (int j = 0; j < 4; ++j) acc[i][j] = fmaf(av[i], bv[j], acc[i][j]);
    }
    __syncthreads();
  }

#pragma unroll
  for (int i = 0; i < 4; ++i) {
    int row = row0 + ty * 4 + i;
    if (row < M) {
      float s = dinv[row];
      uint2 st;
      st.x = packbf(acc[i][0] * s, acc[i][1] * s);
      st.y = packbf(acc[i][2] * s, acc[i][3] * s);
      *(uint2*)&C[(size_t)row * N + col0 + tx * 4] = st;
    }
  }
}

// ---- 128-ch bf16-gather aggregation: H fp32 = dn*(sum bf16 Tp) + b, relu ----
// 16 lanes/node, 8 channels (uint4, 16B) per lane. 256B contiguous per gathered row.
__global__ __launch_bounds__(256) void agg_bf16_kernel(const uint4* __restrict__ Tq,
                                                       const int* __restrict__ row_ptr,
                                                       const int* __restrict__ csr_src,
                                                       const float* __restrict__ dinv,
                                                       const float* __restrict__ bias,
                                                       float* __restrict__ H, int n) {
  int t = blockIdx.x * 256 + threadIdx.x;
  int node = t >> 4;
  int lane = t & 15;   // 16 lanes/node, 8 channels/lane
  if (node >= n) return;

  float dn = dinv[node];
  float a0[8], a1[8], a2[8], a3[8];
#pragma unroll
  for (int c = 0; c < 8; ++c) { a0[c] = 0.f; a1[c] = 0.f; a2[c] = 0.f; a3[c] = 0.f; }
  addq(Tq[(size_t)node * 16 + lane], a0);  // self term (prescaled)

  int beg = row_ptr[node], end = row_ptr[node + 1];
  int e = beg;
  int ae = min(end, (beg + 3) & ~3);
  for (; e < ae; ++e) addq(Tq[(size_t)csr_src[e] * 16 + lane], a0);
  for (; e + 4 <= end; e += 4) {
    int4 s4 = *(const int4*)&csr_src[e];
    uint4 q0 = Tq[(size_t)s4.x * 16 + lane];
    uint4 q1 = Tq[(size_t)s4.y * 16 + lane];
    uint4 q2 = Tq[(size_t)s4.z * 16 + lane];
    uint4 q3 = Tq[(size_t)s4.w * 16 + lane];
    addq(q0, a0); addq(q1, a1); addq(q2, a2); addq(q3, a3);
  }
  for (; e < end; ++e) addq(Tq[(size_t)csr_src[e] * 16 + lane], a0);

  float4 bv0 = *(const float4*)&bias[lane * 8];
  float4 bv1 = *(const float4*)&bias[lane * 8 + 4];
  float bb[8] = {bv0.x, bv0.y, bv0.z, bv0.w, bv1.x, bv1.y, bv1.z, bv1.w};
  float h[8];
#pragma unroll
  for (int c = 0; c < 8; ++c) {
    h[c] = fmaf(dn, (a0[c] + a1[c]) + (a2[c] + a3[c]), bb[c]);
    h[c] = fmaxf(h[c], 0.f);
  }
  float* Hrow = &H[(size_t)node * 128 + lane * 8];
  *(float4*)&Hrow[0] = make_float4(h[0], h[1], h[2], h[3]);
  *(float4*)&Hrow[4] = make_float4(h[4], h[5], h[6], h[7]);
}

// ---- 64-ch bf16-gather aggregation + fused final linear (layer 3) ----
// 8 lanes/node, 8 channels (uint4, 16B) per lane.
__global__ __launch_bounds__(256) void agg64_kernel(const uint4* __restrict__ Tq,
                                                    const int* __restrict__ row_ptr,
                                                    const int* __restrict__ csr_src,
                                                    const float* __restrict__ dinv,
                                                    const float* __restrict__ bias,
                                                    float* __restrict__ H,
                                                    const float* __restrict__ Wout,
                                                    const float* __restrict__ bout,
                                                    float* __restrict__ Out, int n) {
  int t = blockIdx.x * 256 + threadIdx.x;
  int node = t >> 3;
  int lane = t & 7;   // 8 lanes/node, 8 channels/lane
  if (node >= n) return;

  float dn = dinv[node];
  float a0[8], a1[8], a2[8], a3[8];
#pragma unroll
  for (int c = 0; c < 8; ++c) { a0[c] = 0.f; a1[c] = 0.f; a2[c] = 0.f; a3[c] = 0.f; }
  addq(Tq[(size_t)node * 8 + lane], a0);  // self term (prescaled)

  int beg = row_ptr[node], end = row_ptr[node + 1];
  int e = beg;
  int ae = min(end, (beg + 3) & ~3);
  for (; e < ae; ++e) addq(Tq[(size_t)csr_src[e] * 8 + lane], a0);
  for (; e + 4 <= end; e += 4) {
    int4 s4 = *(const int4*)&csr_src[e];
    uint4 q0 = Tq[(size_t)s4.x * 8 + lane];
    uint4 q1 = Tq[(size_t)s4.y * 8 + lane];
    uint4 q2 = Tq[(size_t)s4.z * 8 + lane];
    uint4 q3 = Tq[(size_t)s4.w * 8 + lane];
    addq(q0, a0); addq(q1, a1); addq(q2, a2); addq(q3, a3);
  }
  for (; e < end; ++e) addq(Tq[(size_t)csr_src[e] * 8 + lane], a0);

  float4 bv0 = *(const float4*)&bias[lane * 8];
  float4 bv1 = *(const float4*)&bias[lane * 8 + 4];
  float bb[8] = {bv0.x, bv0.y, bv0.z, bv0.w, bv1.x, bv1.y, bv1.z, bv1.w};
  float h[8];
#pragma unroll
  for (int c = 0; c < 8; ++c)
    h[c] = fmaf(dn, (a0[c] + a1[c]) + (a2[c] + a3[c]), bb[c]);

  float* Hrow = &H[(size_t)node * 64 + lane * 8];
  *(float4*)&Hrow[0] = make_float4(h[0], h[1], h[2], h[3]);
  *(float4*)&Hrow[4] = make_float4(h[4], h[5], h[6], h[7]);

  // fused out = h @ Wout + bout ; lane holds k = lane*8 + c
  int k0 = 8 * lane;
  float p0 = 0.f, p1 = 0.f;
#pragma unroll
  for (int c = 0; c < 8; ++c) {
    p0 = fmaf(h[c], Wout[(k0 + c) * 2 + 0], p0);
    p1 = fmaf(h[c], Wout[(k0 + c) * 2 + 1], p1);
  }
#pragma unroll
  for (int off = 4; off >= 1; off >>= 1) {
    p0 += __shfl_xor(p0, off, 8);
    p1 += __shfl_xor(p1, off, 8);
  }
  if (lane == 0) {
    Out[(size_t)node * 2 + 0] = p0 + bout[0];
    Out[(size_t)node * 2 + 1] = p1 + bout[1];
  }
}

extern "C" void kernel_launch(void* const* d_in, const int* in_sizes, int n_in,
                              void* d_out, int out_size, void* d_ws, size_t ws_size,
                              hipStream_t stream) {
  const float* x    = (const float*)d_in[0];
  const int*   ei   = (const int*)d_in[1];
  const float* W1   = (const float*)d_in[2];
  const float* b1   = (const float*)d_in[3];
  const float* W2   = (const float*)d_in[4];
  const float* b2   = (const float*)d_in[5];
  const float* W3   = (const float*)d_in[6];
  const float* b3   = (const float*)d_in[7];
  const float* Wout = (const float*)d_in[8];
  const float* bout = (const float*)d_in[9];

  const int n = NN, E = NE;
  const int* srcp = ei;
  const int* dstp = ei + E;

  char* ws = (char*)d_ws;
  int*    cntmat  = (int*)(ws + 0);            // 1,045,504 B
  int*    btotal  = (int*)(ws + 1045504);      // pad to 4096
  int*    bbase   = (int*)(ws + 1049600);      // pad to 4096
  int*    offmat  = (int*)(ws + 1053696);      // 1,045,504 B
  int*    row_ptr = (int*)(ws + 2099200);      // 400,016 B
  float*  dinv    = (float*)(ws + 2499216);    // 400,000 B
  int*    csr_src = (int*)(ws + 2899216);      // 12.8 MB (16B aligned)
  ushort* bufT    = (ushort*)(ws + 15699216);  // 25.6 MB bf16 [n,128] (or [n,64] for L3)
  float*  bufH    = (float*)(ws + 41299216);   // 51.2 MB fp32 [n,128]
  int*    store   = (int*)(ws + 41299216);     // 12.8 MB, aliases bufH (dead before agg1)

  float* outp = (float*)d_out;
  float* hemb = (float*)d_out + 2 * n;

  // ---- graph build (atomic-free radix partition) ----
  pcount_kernel<<<NBLK, 256, 0, stream>>>(dstp, cntmat);
  rowsum_kernel<<<NB, 256, 0, stream>>>(cntmat, btotal);
  bucket_scan_kernel<<<1, 1024, 0, stream>>>(btotal, bbase, row_ptr);
  offsets_kernel<<<NB, 256, 0, stream>>>(cntmat, bbase, offmat);
  pscatter_kernel<<<NBLK, 256, 0, stream>>>(srcp, dstp, offmat, store);
  build_kernel<<<NB, 256, 0, stream>>>(btotal, bbase, store, row_ptr, dinv, csr_src);

  // layer 1: Tp1(bf16) = (x @ W1)*dinv ; h1(fp32) = relu(dn*sum + b1)
  gemm_kernel<128><<<dim3((n + 127) / 128, 2), 512, 0, stream>>>(x, W1, dinv, bufT, n);
  agg_bf16_kernel<<<(n * 16 + 255) / 256, 256, 0, stream>>>(
      (const uint4*)bufT, row_ptr, csr_src, dinv, b1, bufH, n);

  // layer 2
  gemm_kernel<128><<<dim3((n + 127) / 128, 2), 512, 0, stream>>>(bufH, W2, dinv, bufT, n);
  agg_bf16_kernel<<<(n * 16 + 255) / 256, 256, 0, stream>>>(
      (const uint4*)bufT, row_ptr, csr_src, dinv, b2, bufH, n);

  // layer 3 (64 ch, bf16 gather) + fused final linear
  gemm_kernel<64><<<dim3((n + 127) / 128, 1), 512, 0, stream>>>(bufH, W3, dinv, bufT, n);
  agg64_kernel<<<(n * 8 + 255) / 256, 256, 0, stream>>>(
      (const uint4*)bufT, row_ptr, csr_src, dinv, b3, hemb, Wout, bout, outp, n);
}